// Round 1
// baseline (353.814 us; speedup 1.0000x reference)
//
#include <hip/hip_runtime.h>

// WindowAttention: B_=4096 windows, N=49, DIM=128, NH=4, HD=32, nW=64.
// One block per window, 256 threads = 4 waves, wave w handles head w.
// bf16 MFMA (16x16x32) for projection + QK^T + PV; fp32 softmax.

typedef short bf16x8 __attribute__((ext_vector_type(8)));
typedef float f32x4 __attribute__((ext_vector_type(4)));

#define DEVI __device__ __forceinline__

DEVI unsigned short f2b(float f) {   // fp32 -> bf16 bits, round-to-nearest-even
    unsigned u = __builtin_bit_cast(unsigned, f);
    u += 0x7fffu + ((u >> 16) & 1u);
    return (unsigned short)(u >> 16);
}

// LDS: 36864 + 18432 + 9604 = 64900 B -> 2 blocks/CU.
// a: qk (proj output Q,K) reused as P (post-softmax probs) after barrier2.
// b: xs (staged input, dead after A-frag hoist) reused as vt (V transposed).
struct __align__(16) Smem {
    union {
        unsigned short qk[2][4][64][32];   // [q/k][head][m 0..63][d 0..31]
        unsigned short p[4][64][72];       // [head][m][n], padded 64->72 (144B rows)
    } a;
    union {
        unsigned short xs[64][136];        // [m][k], padded 128->136 (272B rows)
        unsigned short vt[4][32][72];      // [head][d][n], padded 64->72
    } b;
    float msk[2401];                       // mask[win][49][49] slice
};

__global__ void prep_kernel(const float* __restrict__ w, unsigned short* __restrict__ o) {
    int i = blockIdx.x * 256 + threadIdx.x;      // 12288 float4 = 49152 elems
    float4 v = ((const float4*)w)[i];
    ((ushort4*)o)[i] = make_ushort4(f2b(v.x), f2b(v.y), f2b(v.z), f2b(v.w));
}

template <bool USE_WS>
__global__ __launch_bounds__(256, 2) void wattn_kernel(
    const float* __restrict__ xg, const float* __restrict__ maskg,
    const float* __restrict__ qkvw, const unsigned short* __restrict__ wb,
    const float* __restrict__ qkvb, const float* __restrict__ relt,
    float* __restrict__ outg)
{
    __shared__ Smem sm;
    const int tid  = threadIdx.x;
    const int lane = tid & 63;
    const int wv   = tid >> 6;       // wave index == head index
    const int lr   = lane & 15;      // low 16-lane index
    const int lq   = lane >> 4;      // quad index 0..3
    const int b    = blockIdx.x;

    // ---------------- phase 0: stage x (bf16) + mask (fp32) into LDS ----------------
    const float* xb = xg + (size_t)b * 6272;     // 49*128
    #pragma unroll
    for (int it = 0; it < 7; ++it) {             // 1568 float4 loads
        int i = it * 256 + tid;
        if (i < 1568) {
            float4 v = ((const float4*)xb)[i];
            int row = i >> 5, col = (i & 31) << 2;
            *(ushort4*)&sm.b.xs[row][col] =
                make_ushort4(f2b(v.x), f2b(v.y), f2b(v.z), f2b(v.w));
        }
    }
    for (int i = tid; i < 480; i += 256) {       // zero pad rows 49..63, cols 0..127
        int idx = i << 2;
        *(ushort4*)&sm.b.xs[49 + (idx >> 7)][idx & 127] = make_ushort4(0, 0, 0, 0);
    }
    const float* mw = maskg + (size_t)(b & 63) * 2401;
    for (int i = tid; i < 2401; i += 256) sm.msk[i] = mw[i];
    __syncthreads();

    // ---------------- phase 1: QKV projection ----------------
    // Hoist all A-fragments (x) to registers; xs is dead afterwards.
    bf16x8 af[4][4];                             // [kstep][mtile]
    #pragma unroll
    for (int ks = 0; ks < 4; ++ks)
        #pragma unroll
        for (int mt = 0; mt < 4; ++mt)
            af[ks][mt] = *(const bf16x8*)&sm.b.xs[mt * 16 + lr][ks * 32 + lq * 8];
    __syncthreads();                             // xs dead -> vt region may be written

    #pragma unroll
    for (int j = 0; j < 6; ++j) {
        const int c  = (wv * 6 + j) * 16 + lr;   // output channel 0..383 (wave w -> head w)
        const float bc = qkvb[c];
        f32x4 acc[4];
        #pragma unroll
        for (int mt = 0; mt < 4; ++mt) acc[mt] = f32x4{0.f, 0.f, 0.f, 0.f};
        #pragma unroll
        for (int ks = 0; ks < 4; ++ks) {
            bf16x8 bf;
            if constexpr (USE_WS) {
                bf = *(const bf16x8*)&wb[c * 128 + ks * 32 + lq * 8];
            } else {
                const float4* wp = (const float4*)(qkvw + c * 128 + ks * 32 + lq * 8);
                float4 w0 = wp[0], w1 = wp[1];
                bf16x8 t;
                t[0] = (short)f2b(w0.x); t[1] = (short)f2b(w0.y);
                t[2] = (short)f2b(w0.z); t[3] = (short)f2b(w0.w);
                t[4] = (short)f2b(w1.x); t[5] = (short)f2b(w1.y);
                t[6] = (short)f2b(w1.z); t[7] = (short)f2b(w1.w);
                bf = t;
            }
            #pragma unroll
            for (int mt = 0; mt < 4; ++mt)
                acc[mt] = __builtin_amdgcn_mfma_f32_16x16x32_bf16(af[ks][mt], bf, acc[mt], 0, 0, 0);
        }
        // scatter to Q / K / Vt (torch split order: c = h*96 + d*3 + s)
        const int h2 = c / 96, rem = c % 96, dd = rem / 3, s = rem % 3;
        #pragma unroll
        for (int mt = 0; mt < 4; ++mt)
            #pragma unroll
            for (int r = 0; r < 4; ++r) {
                int m = mt * 16 + lq * 4 + r;
                float v = acc[mt][r] + bc;
                if (s == 0)      sm.a.qk[0][h2][m][dd] = f2b(v * 0.17677669529663687f); // pre-scaled Q
                else if (s == 1) sm.a.qk[1][h2][m][dd] = f2b(v);
                else             sm.b.vt[h2][dd][m]    = f2b(v);
            }
    }
    __syncthreads();

    // ---------------- phase 2: attention (wave = head) ----------------
    const int h = wv;
    bf16x8 qf[4], kf[4];
    #pragma unroll
    for (int t = 0; t < 4; ++t) {
        qf[t] = *(const bf16x8*)&sm.a.qk[0][h][t * 16 + lr][lq * 8];
        kf[t] = *(const bf16x8*)&sm.a.qk[1][h][t * 16 + lr][lq * 8];
    }
    f32x4 s4[4][4];
    #pragma unroll
    for (int mt = 0; mt < 4; ++mt)
        #pragma unroll
        for (int nt = 0; nt < 4; ++nt) {
            f32x4 z = f32x4{0.f, 0.f, 0.f, 0.f};
            s4[mt][nt] = __builtin_amdgcn_mfma_f32_16x16x32_bf16(qf[mt], kf[nt], z, 0, 0, 0);
        }

    // + relative-position bias (closed form) + shift mask; pad cols -> -1e30
    #pragma unroll
    for (int mt = 0; mt < 4; ++mt)
        #pragma unroll
        for (int r = 0; r < 4; ++r) {
            int m  = mt * 16 + lq * 4 + r;
            int mi = m < 48 ? m : 48;
            int md = mi / 7, mm = mi - md * 7;
            #pragma unroll
            for (int nt = 0; nt < 4; ++nt) {
                int n  = nt * 16 + lr;
                int ni = n < 48 ? n : 48;
                int nd = ni / 7, nm = ni - nd * 7;
                int ridx = (md - nd + 6) * 13 + (mm - nm + 6);
                float v = s4[mt][nt][r] + relt[ridx * 4 + h] + sm.msk[mi * 49 + ni];
                s4[mt][nt][r] = (n < 49) ? v : -1e30f;
            }
        }
    __syncthreads();   // all Q/K/mask LDS reads done -> P may overwrite qk region

    // row softmax (rows live across 16 lanes of same quad + 4 n-tiles)
    #pragma unroll
    for (int mt = 0; mt < 4; ++mt)
        #pragma unroll
        for (int r = 0; r < 4; ++r) {
            float mx = fmaxf(fmaxf(s4[mt][0][r], s4[mt][1][r]),
                             fmaxf(s4[mt][2][r], s4[mt][3][r]));
            mx = fmaxf(mx, __shfl_xor(mx, 1));
            mx = fmaxf(mx, __shfl_xor(mx, 2));
            mx = fmaxf(mx, __shfl_xor(mx, 4));
            mx = fmaxf(mx, __shfl_xor(mx, 8));
            float sum = 0.f;
            #pragma unroll
            for (int nt = 0; nt < 4; ++nt) {
                float e = __expf(s4[mt][nt][r] - mx);
                s4[mt][nt][r] = e;
                sum += e;
            }
            sum += __shfl_xor(sum, 1);
            sum += __shfl_xor(sum, 2);
            sum += __shfl_xor(sum, 4);
            sum += __shfl_xor(sum, 8);
            float inv = 1.f / sum;
            int m = mt * 16 + lq * 4 + r;
            #pragma unroll
            for (int nt = 0; nt < 4; ++nt)
                sm.a.p[h][m][nt * 16 + lr] = f2b(s4[mt][nt][r] * inv);
        }

    // PV: out[m][d] = sum_n P[m][n] * Vt[d][n]
    bf16x8 vf[2][2];
    #pragma unroll
    for (int dt = 0; dt < 2; ++dt)
        #pragma unroll
        for (int kt = 0; kt < 2; ++kt)
            vf[dt][kt] = *(const bf16x8*)&sm.b.vt[h][dt * 16 + lr][kt * 32 + lq * 8];
    f32x4 o[4][2];
    #pragma unroll
    for (int mt = 0; mt < 4; ++mt)
        #pragma unroll
        for (int dt = 0; dt < 2; ++dt) o[mt][dt] = f32x4{0.f, 0.f, 0.f, 0.f};
    #pragma unroll
    for (int mt = 0; mt < 4; ++mt)
        #pragma unroll
        for (int kt = 0; kt < 2; ++kt) {
            bf16x8 pf = *(const bf16x8*)&sm.a.p[h][mt * 16 + lr][kt * 32 + lq * 8];
            #pragma unroll
            for (int dt = 0; dt < 2; ++dt)
                o[mt][dt] = __builtin_amdgcn_mfma_f32_16x16x32_bf16(pf, vf[dt][kt], o[mt][dt], 0, 0, 0);
        }

    // store: out[b][m][h*32 + d], fp32, coalesced over lr
    float* ob = outg + (size_t)b * 6272;
    #pragma unroll
    for (int mt = 0; mt < 4; ++mt)
        #pragma unroll
        for (int r = 0; r < 4; ++r) {
            int m = mt * 16 + lq * 4 + r;
            if (m < 49) {
                #pragma unroll
                for (int dt = 0; dt < 2; ++dt)
                    ob[m * 128 + h * 32 + dt * 16 + lr] = o[mt][dt][r];
            }
        }
}

extern "C" void kernel_launch(void* const* d_in, const int* in_sizes, int n_in,
                              void* d_out, int out_size, void* d_ws, size_t ws_size,
                              hipStream_t stream) {
    const float* x    = (const float*)d_in[0];
    const float* mask = (const float*)d_in[1];
    const float* qkvw = (const float*)d_in[2];
    const float* qkvb = (const float*)d_in[3];
    const float* relt = (const float*)d_in[4];
    float* out = (float*)d_out;

    const bool use_ws = (d_ws != nullptr) && (ws_size >= 49152 * sizeof(unsigned short));
    if (use_ws) {
        unsigned short* wbf = (unsigned short*)d_ws;
        prep_kernel<<<48, 256, 0, stream>>>(qkvw, wbf);   // fp32 -> bf16 weights
        wattn_kernel<true><<<4096, 256, 0, stream>>>(x, mask, qkvw, wbf, qkvb, relt, out);
    } else {
        wattn_kernel<false><<<4096, 256, 0, stream>>>(x, mask, qkvw, nullptr, qkvb, relt, out);
    }
}

// Round 2
// 310.684 us; speedup vs baseline: 1.1388x; 1.1388x over previous
//
#include <hip/hip_runtime.h>

// WindowAttention: B_=4096 windows, N=49, DIM=128, NH=4, HD=32, nW=64.
// One block per window, 512 threads = 8 waves; wave w -> (head = w&3, m-half = w>>2).
// bf16 MFMA 16x16x32. S is computed TRANSPOSED (S^T = K*Q^T) so softmax rows are
// in-lane and P feeds PV as a B-fragment via shuffles (no P LDS round-trip).

typedef short bf16x8 __attribute__((ext_vector_type(8)));
typedef float f32x4 __attribute__((ext_vector_type(4)));

#define DEVI __device__ __forceinline__

DEVI unsigned short f2b(float f) {   // fp32 -> bf16 bits, round-to-nearest-even
    unsigned u = __builtin_bit_cast(unsigned, f);
    u += 0x7fffu + ((u >> 16) & 1u);
    return (unsigned short)(u >> 16);
}

// LDS: 32768 + 18432 = 51200 B -> 3 blocks/CU (24 waves/CU).
struct __align__(16) Smem {
    unsigned short qk[2][4][64][32];   // [q/k][head][m 0..63][d 0..31]; Q pre-scaled
    union {
        unsigned short xs[64][136];    // staged x, 272 B rows (16B-aligned)
        unsigned short vt[4][32][72];  // V^T [head][d][n], 144 B rows
    } b;
};

__global__ void prep_kernel(const float* __restrict__ w, unsigned short* __restrict__ o) {
    int i = blockIdx.x * 256 + threadIdx.x;      // 12288 float4 = 49152 elems
    float4 v = ((const float4*)w)[i];
    ((ushort4*)o)[i] = make_ushort4(f2b(v.x), f2b(v.y), f2b(v.z), f2b(v.w));
}

template <bool USE_WS>
__global__ __launch_bounds__(512, 6) void wattn_kernel(
    const float* __restrict__ xg, const float* __restrict__ maskg,
    const float* __restrict__ qkvw, const unsigned short* __restrict__ wb,
    const float* __restrict__ qkvb, const float* __restrict__ relt,
    float* __restrict__ outg)
{
    __shared__ Smem sm;
    const int tid  = threadIdx.x;
    const int lane = tid & 63;
    const int wv   = tid >> 6;       // 0..7
    const int h    = wv & 3;         // head
    const int half = wv >> 2;        // m-half: rows [half*32, half*32+32)
    const int lr   = lane & 15;
    const int lq   = lane >> 4;
    const int bI   = blockIdx.x;

    // ---------------- phase 0: stage x (bf16) into LDS ----------------
    const float* xb = xg + (size_t)bI * 6272;    // 49*128
    #pragma unroll
    for (int it = 0; it < 4; ++it) {             // 1568 float4 loads over 512 thr
        int i = it * 512 + tid;
        if (i < 1568) {
            float4 v = ((const float4*)xb)[i];
            int row = i >> 5, col = (i & 31) << 2;
            *(ushort4*)&sm.b.xs[row][col] =
                make_ushort4(f2b(v.x), f2b(v.y), f2b(v.z), f2b(v.w));
        }
    }
    if (tid < 480) {                             // zero rows 49..63
        int idx = tid << 2;
        *(ushort4*)&sm.b.xs[49 + (idx >> 7)][idx & 127] = make_ushort4(0, 0, 0, 0);
    }
    __syncthreads();

    // ---------------- phase 1: QKV projection (wave = head h, m-half) ----------------
    bf16x8 af[4][2];                             // [kstep][local mtile]
    #pragma unroll
    for (int ks = 0; ks < 4; ++ks)
        #pragma unroll
        for (int mtl = 0; mtl < 2; ++mtl)
            af[ks][mtl] = *(const bf16x8*)&sm.b.xs[(half * 2 + mtl) * 16 + lr][ks * 32 + lq * 8];
    __syncthreads();                             // xs dead -> vt region may be written

    unsigned short* sbase = (unsigned short*)&sm;
    #pragma unroll
    for (int j = 0; j < 6; ++j) {
        const int c   = (h * 6 + j) * 16 + lr;   // output channel (head h's channels)
        const float bc = qkvb[c];
        const int rem = j * 16 + lr;             // c - h*96
        const int dd  = rem / 3, s = rem % 3;    // torch split: c = h*96 + d*3 + s
        const float mulv = (s == 0) ? 0.17677669529663687f : 1.0f;  // pre-scale Q
        f32x4 acc[2];
        acc[0] = f32x4{0.f, 0.f, 0.f, 0.f};
        acc[1] = f32x4{0.f, 0.f, 0.f, 0.f};
        #pragma unroll
        for (int ks = 0; ks < 4; ++ks) {
            bf16x8 bf;
            if constexpr (USE_WS) {
                bf = *(const bf16x8*)&wb[c * 128 + ks * 32 + lq * 8];
            } else {
                const float4* wp = (const float4*)(qkvw + c * 128 + ks * 32 + lq * 8);
                float4 w0 = wp[0], w1 = wp[1];
                bf16x8 t;
                t[0] = (short)f2b(w0.x); t[1] = (short)f2b(w0.y);
                t[2] = (short)f2b(w0.z); t[3] = (short)f2b(w0.w);
                t[4] = (short)f2b(w1.x); t[5] = (short)f2b(w1.y);
                t[6] = (short)f2b(w1.z); t[7] = (short)f2b(w1.w);
                bf = t;
            }
            #pragma unroll
            for (int mtl = 0; mtl < 2; ++mtl)
                acc[mtl] = __builtin_amdgcn_mfma_f32_16x16x32_bf16(af[ks][mtl], bf, acc[mtl], 0, 0, 0);
        }
        // scatter via computed LDS offset (one non-divergent ds_write_b16 per value)
        #pragma unroll
        for (int mtl = 0; mtl < 2; ++mtl)
            #pragma unroll
            for (int r = 0; r < 4; ++r) {
                int m = (half * 2 + mtl) * 16 + lq * 4 + r;
                int soff = (s == 2) ? (16384 + (h * 32 + dd) * 72 + m)     // vt[h][dd][m]
                                    : (s * 8192 + h * 2048 + m * 32 + dd); // qk[s][h][m][dd]
                sbase[soff] = f2b((acc[mtl][r] + bc) * mulv);
            }
    }
    __syncthreads();

    // ---------------- phase 2: attention ----------------
    bf16x8 kf[4];
    #pragma unroll
    for (int t = 0; t < 4; ++t)
        kf[t] = *(const bf16x8*)&sm.qk[1][h][t * 16 + lr][lq * 8];

    const float* mw = maskg + (size_t)(bI & 63) * 2401;
    float* ob = outg + (size_t)bI * 6272;
    const int src0 = ((lq & 1) * 2) * 16 + lr;
    const int src1 = src0 + 16;
    const bool up  = (lq >= 2);

    #pragma unroll
    for (int bl = 0; bl < 2; ++bl) {
        const int mt = half * 2 + bl;
        bf16x8 qf = *(const bf16x8*)&sm.qk[0][h][mt * 16 + lr][lq * 8];

        // S^T tiles: st[a][r] = S[m = mt*16+lr][n = a*16 + lq*4 + r]
        f32x4 st[4];
        #pragma unroll
        for (int a = 0; a < 4; ++a) {
            f32x4 z = f32x4{0.f, 0.f, 0.f, 0.f};
            st[a] = __builtin_amdgcn_mfma_f32_16x16x32_bf16(kf[a], qf, z, 0, 0, 0);
        }

        const int m  = mt * 16 + lr;
        const int mi = m < 48 ? m : 48;
        const int md = mi / 7, mm = mi - md * 7;
        #pragma unroll
        for (int a = 0; a < 4; ++a)
            #pragma unroll
            for (int r = 0; r < 4; ++r) {
                int n  = a * 16 + lq * 4 + r;
                int ni = n < 48 ? n : 48;
                int nd = ni / 7, nm = ni - nd * 7;
                int ridx = (md - nd + 6) * 13 + (mm - nm + 6);
                float v = st[a][r] + relt[ridx * 4 + h] + mw[mi * 49 + ni];
                st[a][r] = (n < 49) ? v : -1e30f;
            }

        // softmax over row m: 16 in-lane values + lanes {lr, lr+16, lr+32, lr+48}
        float mx = -3.4e38f;
        #pragma unroll
        for (int a = 0; a < 4; ++a)
            #pragma unroll
            for (int r = 0; r < 4; ++r) mx = fmaxf(mx, st[a][r]);
        mx = fmaxf(mx, __shfl_xor(mx, 16));
        mx = fmaxf(mx, __shfl_xor(mx, 32));
        float sum = 0.f;
        #pragma unroll
        for (int a = 0; a < 4; ++a)
            #pragma unroll
            for (int r = 0; r < 4; ++r) {
                float e = __expf(st[a][r] - mx);
                st[a][r] = e;
                sum += e;
            }
        sum += __shfl_xor(sum, 16);
        sum += __shfl_xor(sum, 32);
        const float inv = 1.f / sum;

        // pack P row: pk[a] = bf16{r0,r1},{r2,r3}
        unsigned pk[4][2];
        #pragma unroll
        for (int a = 0; a < 4; ++a) {
            pk[a][0] = (unsigned)f2b(st[a][0] * inv) | ((unsigned)f2b(st[a][1] * inv) << 16);
            pk[a][1] = (unsigned)f2b(st[a][2] * inv) | ((unsigned)f2b(st[a][3] * inv) << 16);
        }

        // PV: out^T[d][m] = sum_n Vt[d][n] * P[m][n]; B-frag of P via shuffles.
        f32x4 o[2];
        o[0] = f32x4{0.f, 0.f, 0.f, 0.f};
        o[1] = f32x4{0.f, 0.f, 0.f, 0.f};
        #pragma unroll
        for (int kt = 0; kt < 2; ++kt) {
            // receiver needs nt = 2kt + (lq>>1); fetch both and select
            unsigned ea0 = (unsigned)__shfl((int)pk[2 * kt][0], src0);
            unsigned ea1 = (unsigned)__shfl((int)pk[2 * kt][1], src0);
            unsigned ea2 = (unsigned)__shfl((int)pk[2 * kt][0], src1);
            unsigned ea3 = (unsigned)__shfl((int)pk[2 * kt][1], src1);
            unsigned eb0 = (unsigned)__shfl((int)pk[2 * kt + 1][0], src0);
            unsigned eb1 = (unsigned)__shfl((int)pk[2 * kt + 1][1], src0);
            unsigned eb2 = (unsigned)__shfl((int)pk[2 * kt + 1][0], src1);
            unsigned eb3 = (unsigned)__shfl((int)pk[2 * kt + 1][1], src1);
            union { unsigned u[4]; bf16x8 v; } pu;
            pu.u[0] = up ? eb0 : ea0;
            pu.u[1] = up ? eb1 : ea1;
            pu.u[2] = up ? eb2 : ea2;
            pu.u[3] = up ? eb3 : ea3;
            #pragma unroll
            for (int dt = 0; dt < 2; ++dt) {
                bf16x8 vf = *(const bf16x8*)&sm.b.vt[h][dt * 16 + lr][kt * 32 + lq * 8];
                o[dt] = __builtin_amdgcn_mfma_f32_16x16x32_bf16(vf, pu.v, o[dt], 0, 0, 0);
            }
        }

        // store: out[m][h*32 + d], d = dt*16 + lq*4 + r -> float4 per (dt)
        if (m < 49) {
            #pragma unroll
            for (int dt = 0; dt < 2; ++dt) {
                float4 v = make_float4(o[dt][0], o[dt][1], o[dt][2], o[dt][3]);
                *(float4*)&ob[m * 128 + h * 32 + dt * 16 + lq * 4] = v;
            }
        }
    }
}

extern "C" void kernel_launch(void* const* d_in, const int* in_sizes, int n_in,
                              void* d_out, int out_size, void* d_ws, size_t ws_size,
                              hipStream_t stream) {
    const float* x    = (const float*)d_in[0];
    const float* mask = (const float*)d_in[1];
    const float* qkvw = (const float*)d_in[2];
    const float* qkvb = (const float*)d_in[3];
    const float* relt = (const float*)d_in[4];
    float* out = (float*)d_out;

    const bool use_ws = (d_ws != nullptr) && (ws_size >= 49152 * sizeof(unsigned short));
    if (use_ws) {
        unsigned short* wbf = (unsigned short*)d_ws;
        prep_kernel<<<48, 256, 0, stream>>>(qkvw, wbf);   // fp32 -> bf16 weights
        wattn_kernel<true><<<4096, 512, 0, stream>>>(x, mask, qkvw, wbf, qkvb, relt, out);
    } else {
        wattn_kernel<false><<<4096, 512, 0, stream>>>(x, mask, qkvw, nullptr, qkvb, relt, out);
    }
}

// Round 3
// 266.664 us; speedup vs baseline: 1.3268x; 1.1651x over previous
//
#include <hip/hip_runtime.h>

// WindowAttention: B_=4096 windows, N=49, DIM=128, NH=4, HD=32, nW=64.
// One block per window, 512 threads = 8 waves; wave w -> (head = w&3, m-half = w>>2).
// bf16 MFMA 16x16x32. S computed transposed (S^T = K*Q^T): softmax rows in-lane,
// P feeds PV as B-fragment via shuffles (no P LDS round-trip).
// R3: prep kernel permutes weights (row c' = s*128+h*32+d, Q pre-scaled) so the
// phase-1 LDS scatter is lane-linear (b64 V writes, ~4-way Q/K writes), and
// precomputes comb[w][h][n][m] = mask + rel-bias, folded into the QK^T MFMA C-operand.

typedef short bf16x8 __attribute__((ext_vector_type(8)));
typedef float f32x4 __attribute__((ext_vector_type(4)));

#define DEVI __device__ __forceinline__

DEVI unsigned short f2b(float f) {   // fp32 -> bf16 bits, round-to-nearest-even
    unsigned u = __builtin_bit_cast(unsigned, f);
    u += 0x7fffu + ((u >> 16) & 1u);
    return (unsigned short)(u >> 16);
}

#define WS_BIAS_OFF 98304
#define WS_COMB_OFF 131072
#define WS_NEED     (131072u + 64u * 4u * 2401u * 4u)

__global__ void prep_kernel(const float* __restrict__ qkvw, const float* __restrict__ qkvb,
                            const float* __restrict__ maskg, const float* __restrict__ relt,
                            unsigned short* __restrict__ wb, float* __restrict__ bb,
                            float* __restrict__ comb) {
    const int blk = blockIdx.x;
    const int tid = threadIdx.x;
    if (blk < 384) {
        // permuted weight row c' = blk = s*128 + h*32 + d  <-  torch row c = h*96 + d*3 + s
        const int s = blk >> 7, r7 = blk & 127, h = r7 >> 5, d = r7 & 31;
        const int c = h * 96 + d * 3 + s;
        const float mul = (s == 0) ? 0.17677669529663687f : 1.0f;
        if (tid < 128) wb[blk * 128 + tid] = f2b(qkvw[c * 128 + tid] * mul);
        if (tid == 128) bb[blk] = qkvb[c] * mul;
    } else {
        const int wh = blk - 384;            // (w,h) = 0..255
        const int w = wh >> 2, h = wh & 3;
        const float* mw = maskg + w * 2401;
        float* cbp = comb + wh * 2401;
        for (int i = tid; i < 2401; i += 256) {
            int n = i / 49, m = i - n * 49;
            int md = m / 7, mm = m - md * 7;
            int nd = n / 7, nm = n - nd * 7;
            int ridx = (md - nd + 6) * 13 + (mm - nm + 6);
            cbp[i] = mw[m * 49 + n] + relt[ridx * 4 + h];   // comb[n][m]
        }
    }
}

// LDS: 32768 + 18432 = 51200 B -> 3 blocks/CU (24 waves/CU).
struct __align__(16) Smem {
    unsigned short qk[2][4][64][32];   // [q/k][head][m][d]; Q pre-scaled
    union {
        unsigned short xs[64][136];    // staged x, 272 B rows
        unsigned short vt[4][32][72];  // V^T [head][d][n], 144 B rows
    } b;
};

template <bool USE_WS>
__global__ __launch_bounds__(512, 6) void wattn_kernel(
    const float* __restrict__ xg, const unsigned short* __restrict__ wb,
    const float* __restrict__ bb, const float* __restrict__ comb,
    const float* __restrict__ maskg, const float* __restrict__ qkvw,
    const float* __restrict__ qkvb, const float* __restrict__ relt,
    float* __restrict__ outg)
{
    __shared__ Smem sm;
    const int tid  = threadIdx.x;
    const int lane = tid & 63;
    const int wv   = tid >> 6;       // 0..7
    const int h    = wv & 3;         // head
    const int half = wv >> 2;        // m-half
    const int lr   = lane & 15;
    const int lq   = lane >> 4;
    const int bI   = blockIdx.x;

    // ---------------- phase 0: stage x (bf16) into LDS ----------------
    const float* xb = xg + (size_t)bI * 6272;
    #pragma unroll
    for (int it = 0; it < 4; ++it) {
        int i = it * 512 + tid;
        if (i < 1568) {
            float4 v = ((const float4*)xb)[i];
            int row = i >> 5, col = (i & 31) << 2;
            *(ushort4*)&sm.b.xs[row][col] =
                make_ushort4(f2b(v.x), f2b(v.y), f2b(v.z), f2b(v.w));
        }
    }
    if (tid < 480) {                 // zero rows 49..63
        int idx = tid << 2;
        *(ushort4*)&sm.b.xs[49 + (idx >> 7)][idx & 127] = make_ushort4(0, 0, 0, 0);
    }
    __syncthreads();

    // ---------------- phase 1: QKV projection ----------------
    bf16x8 af[4][2];
    #pragma unroll
    for (int ks = 0; ks < 4; ++ks)
        #pragma unroll
        for (int mtl = 0; mtl < 2; ++mtl)
            af[ks][mtl] = *(const bf16x8*)&sm.b.xs[(half * 2 + mtl) * 16 + lr][ks * 32 + lq * 8];
    __syncthreads();                 // xs dead -> vt region may be written

    if constexpr (USE_WS) {
        // permuted weights: tile j -> (s = j>>1, dhalf = j&1), channel lane-linear
        #pragma unroll
        for (int j = 0; j < 6; ++j) {
            const int s     = j >> 1;
            const int dhalf = j & 1;
            const int cp    = s * 128 + h * 32 + dhalf * 16 + lr;
            const int dd    = dhalf * 16 + lr;
            const float bc  = bb[cp];
            f32x4 acc[2];
            acc[0] = f32x4{0.f, 0.f, 0.f, 0.f};
            acc[1] = f32x4{0.f, 0.f, 0.f, 0.f};
            #pragma unroll
            for (int ks = 0; ks < 4; ++ks) {
                bf16x8 bf = *(const bf16x8*)&wb[cp * 128 + ks * 32 + lq * 8];
                #pragma unroll
                for (int mtl = 0; mtl < 2; ++mtl)
                    acc[mtl] = __builtin_amdgcn_mfma_f32_16x16x32_bf16(af[ks][mtl], bf, acc[mtl], 0, 0, 0);
            }
            #pragma unroll
            for (int mtl = 0; mtl < 2; ++mtl) {
                const int m0 = (half * 2 + mtl) * 16 + lq * 4;
                if (s == 2) {
                    *(ushort4*)&sm.b.vt[h][dd][m0] =
                        make_ushort4(f2b(acc[mtl][0] + bc), f2b(acc[mtl][1] + bc),
                                     f2b(acc[mtl][2] + bc), f2b(acc[mtl][3] + bc));
                } else {
                    #pragma unroll
                    for (int r = 0; r < 4; ++r)
                        sm.qk[s][h][m0 + r][dd] = f2b(acc[mtl][r] + bc);
                }
            }
        }
    } else {
        // fallback: unpermuted weights, scalar scatter (R2 path)
        unsigned short* sbase = (unsigned short*)&sm;
        #pragma unroll
        for (int j = 0; j < 6; ++j) {
            const int c = (h * 6 + j) * 16 + lr;
            const float bc = qkvb[c];
            const int rem = j * 16 + lr;
            const int dd = rem / 3, s = rem % 3;
            const float mulv = (s == 0) ? 0.17677669529663687f : 1.0f;
            f32x4 acc[2];
            acc[0] = f32x4{0.f, 0.f, 0.f, 0.f};
            acc[1] = f32x4{0.f, 0.f, 0.f, 0.f};
            #pragma unroll
            for (int ks = 0; ks < 4; ++ks) {
                const float4* wp = (const float4*)(qkvw + c * 128 + ks * 32 + lq * 8);
                float4 w0 = wp[0], w1 = wp[1];
                bf16x8 t;
                t[0] = (short)f2b(w0.x); t[1] = (short)f2b(w0.y);
                t[2] = (short)f2b(w0.z); t[3] = (short)f2b(w0.w);
                t[4] = (short)f2b(w1.x); t[5] = (short)f2b(w1.y);
                t[6] = (short)f2b(w1.z); t[7] = (short)f2b(w1.w);
                #pragma unroll
                for (int mtl = 0; mtl < 2; ++mtl)
                    acc[mtl] = __builtin_amdgcn_mfma_f32_16x16x32_bf16(af[ks][mtl], t, acc[mtl], 0, 0, 0);
            }
            #pragma unroll
            for (int mtl = 0; mtl < 2; ++mtl)
                #pragma unroll
                for (int r = 0; r < 4; ++r) {
                    int m = (half * 2 + mtl) * 16 + lq * 4 + r;
                    int soff = (s == 2) ? (16384 + (h * 32 + dd) * 72 + m)
                                        : (s * 8192 + h * 2048 + m * 32 + dd);
                    sbase[soff] = f2b((acc[mtl][r] + bc) * mulv);
                }
        }
    }
    __syncthreads();

    // ---------------- phase 2: attention ----------------
    bf16x8 kf[4];
    #pragma unroll
    for (int t = 0; t < 4; ++t)
        kf[t] = *(const bf16x8*)&sm.qk[1][h][t * 16 + lr][lq * 8];

    const float* cwh = comb + (size_t)((bI & 63) * 4 + h) * 2401;
    const float* mw  = maskg + (size_t)(bI & 63) * 2401;
    float* ob = outg + (size_t)bI * 6272;
    const int src0 = ((lq & 1) * 2) * 16 + lr;
    const int src1 = src0 + 16;
    const bool up  = (lq >= 2);

    #pragma unroll
    for (int bl = 0; bl < 2; ++bl) {
        const int mt = half * 2 + bl;
        const int m  = mt * 16 + lr;
        const int mi = m < 48 ? m : 48;

        f32x4 st[4];
        if constexpr (USE_WS) {
            // C-operand: comb[n][m] (+ -1e30 column mask), coalesced over lr
            f32x4 cc[4];
            #pragma unroll
            for (int a = 0; a < 4; ++a)
                #pragma unroll
                for (int r = 0; r < 4; ++r) {
                    int n = a * 16 + lq * 4 + r;
                    cc[a][r] = (n < 49) ? cwh[n * 49 + mi] : -1e30f;
                }
            bf16x8 qf = *(const bf16x8*)&sm.qk[0][h][m][lq * 8];
            #pragma unroll
            for (int a = 0; a < 4; ++a)
                st[a] = __builtin_amdgcn_mfma_f32_16x16x32_bf16(kf[a], qf, cc[a], 0, 0, 0);
        } else {
            bf16x8 qf = *(const bf16x8*)&sm.qk[0][h][m][lq * 8];
            #pragma unroll
            for (int a = 0; a < 4; ++a) {
                f32x4 z = f32x4{0.f, 0.f, 0.f, 0.f};
                st[a] = __builtin_amdgcn_mfma_f32_16x16x32_bf16(kf[a], qf, z, 0, 0, 0);
            }
            const int md = mi / 7, mm = mi - md * 7;
            #pragma unroll
            for (int a = 0; a < 4; ++a)
                #pragma unroll
                for (int r = 0; r < 4; ++r) {
                    int n = a * 16 + lq * 4 + r;
                    int ni = n < 48 ? n : 48;
                    int nd = ni / 7, nm = ni - nd * 7;
                    int ridx = (md - nd + 6) * 13 + (mm - nm + 6);
                    float v = st[a][r] + relt[ridx * 4 + h] + mw[mi * 49 + ni];
                    st[a][r] = (n < 49) ? v : -1e30f;
                }
        }

        // softmax over row m (16 in-lane + lanes {lr, lr+16, lr+32, lr+48})
        float mx = -3.4e38f;
        #pragma unroll
        for (int a = 0; a < 4; ++a)
            #pragma unroll
            for (int r = 0; r < 4; ++r) mx = fmaxf(mx, st[a][r]);
        mx = fmaxf(mx, __shfl_xor(mx, 16));
        mx = fmaxf(mx, __shfl_xor(mx, 32));
        float sum = 0.f;
        #pragma unroll
        for (int a = 0; a < 4; ++a)
            #pragma unroll
            for (int r = 0; r < 4; ++r) {
                float e = __expf(st[a][r] - mx);
                st[a][r] = e;
                sum += e;
            }
        sum += __shfl_xor(sum, 16);
        sum += __shfl_xor(sum, 32);
        const float inv = 1.f / sum;

        unsigned pk[4][2];
        #pragma unroll
        for (int a = 0; a < 4; ++a) {
            pk[a][0] = (unsigned)f2b(st[a][0] * inv) | ((unsigned)f2b(st[a][1] * inv) << 16);
            pk[a][1] = (unsigned)f2b(st[a][2] * inv) | ((unsigned)f2b(st[a][3] * inv) << 16);
        }

        // PV: out^T[d][m] = sum_n Vt[d][n] * P[m][n]; P B-frag via shuffles
        f32x4 o[2];
        o[0] = f32x4{0.f, 0.f, 0.f, 0.f};
        o[1] = f32x4{0.f, 0.f, 0.f, 0.f};
        #pragma unroll
        for (int kt = 0; kt < 2; ++kt) {
            unsigned ea0 = (unsigned)__shfl((int)pk[2 * kt][0], src0);
            unsigned ea1 = (unsigned)__shfl((int)pk[2 * kt][1], src0);
            unsigned ea2 = (unsigned)__shfl((int)pk[2 * kt][0], src1);
            unsigned ea3 = (unsigned)__shfl((int)pk[2 * kt][1], src1);
            unsigned eb0 = (unsigned)__shfl((int)pk[2 * kt + 1][0], src0);
            unsigned eb1 = (unsigned)__shfl((int)pk[2 * kt + 1][1], src0);
            unsigned eb2 = (unsigned)__shfl((int)pk[2 * kt + 1][0], src1);
            unsigned eb3 = (unsigned)__shfl((int)pk[2 * kt + 1][1], src1);
            union { unsigned u[4]; bf16x8 v; } pu;
            pu.u[0] = up ? eb0 : ea0;
            pu.u[1] = up ? eb1 : ea1;
            pu.u[2] = up ? eb2 : ea2;
            pu.u[3] = up ? eb3 : ea3;
            #pragma unroll
            for (int dt = 0; dt < 2; ++dt) {
                bf16x8 vf = *(const bf16x8*)&sm.b.vt[h][dt * 16 + lr][kt * 32 + lq * 8];
                o[dt] = __builtin_amdgcn_mfma_f32_16x16x32_bf16(vf, pu.v, o[dt], 0, 0, 0);
            }
        }

        if (m < 49) {
            #pragma unroll
            for (int dt = 0; dt < 2; ++dt) {
                float4 v = make_float4(o[dt][0], o[dt][1], o[dt][2], o[dt][3]);
                *(float4*)&ob[m * 128 + h * 32 + dt * 16 + lq * 4] = v;
            }
        }
    }
}

extern "C" void kernel_launch(void* const* d_in, const int* in_sizes, int n_in,
                              void* d_out, int out_size, void* d_ws, size_t ws_size,
                              hipStream_t stream) {
    const float* x    = (const float*)d_in[0];
    const float* mask = (const float*)d_in[1];
    const float* qkvw = (const float*)d_in[2];
    const float* qkvb = (const float*)d_in[3];
    const float* relt = (const float*)d_in[4];
    float* out = (float*)d_out;

    if (d_ws != nullptr && ws_size >= (size_t)WS_NEED) {
        unsigned short* wbf = (unsigned short*)d_ws;
        float* bbf  = (float*)((char*)d_ws + WS_BIAS_OFF);
        float* comb = (float*)((char*)d_ws + WS_COMB_OFF);
        prep_kernel<<<640, 256, 0, stream>>>(qkvw, qkvb, mask, relt, wbf, bbf, comb);
        wattn_kernel<true><<<4096, 512, 0, stream>>>(x, wbf, bbf, comb, mask, qkvw, qkvb, relt, out);
    } else {
        wattn_kernel<false><<<4096, 512, 0, stream>>>(x, nullptr, nullptr, nullptr, mask, qkvw, qkvb, relt, out);
    }
}